// Round 4
// baseline (568.545 us; speedup 1.0000x reference)
//
#include <hip/hip_runtime.h>
#include <math.h>

#define H      1024
#define NA     512
#define NI     256
#define SEQ    4096
#define BATCH  4
#define NTOK   (BATCH*SEQ)      // 16384
#define SINKN  4
#define RECENTN 19
#define MIDN   (SEQ - SINKN - RECENTN)   // 4073
#define KSEL   2025
#define CHK    16

#define TT   128                // tokens per tile
#define UT   128                // units per tile
#define KC   32                 // k-chunk staged in LDS
#define ATT_BLOCKS ((NTOK/TT) * (NA/UT))   // 128*4 = 512
#define IMP_BLOCKS ((NTOK/TT) * (NI/UT))   // 128*2 = 256

// ---------------------------------------------------------------------------
// Kernel 1 (v5): register-blocked GEMM, 128x128 tile, 8x8 per-thread.
//  - __launch_bounds__(256,2): budget 256 regs so the 32 prefetch floats stay
//    in registers (v3 spilled them: 203MB scratch WRITE_SIZE). Grid is 3
//    blocks/CU anyway.
//  - A staged transposed [KC][128] with XOR column swizzle: element (row,col)
//    at col_phys = col ^ ((row>>2 & 3)<<3). v5 fixes v4's bug: the swizzle
//    must be XOR (v4 used a plain add, wrong for at>=8 -> wrong mask).
//    Write banks: (at ^ ((aq&3)<<3)) & 31 -> each bank hit by exactly 2
//    lanes = free. Reads fold to ty ^ ((h>>2)&3), 16B-aligned b128
//    broadcasts, conflict-free.
//  - B quad-swizzle (q^(q>>3), involution): reads 2-way (free), writes clean.
// Deterministic summation order -> selection identical to fp32 reference.
// ---------------------------------------------------------------------------
__global__ __launch_bounds__(256, 2) void score_gemm_kernel(
    const float* __restrict__ keys, const float* __restrict__ values,
    const float* __restrict__ W1a, const float* __restrict__ b1a,
    const float* __restrict__ W2a,
    const float* __restrict__ W1i, const float* __restrict__ b1i,
    const float* __restrict__ W2i,
    float* __restrict__ part)
{
    __shared__ __align__(16) float smem[KC * 128 + KC * UT];   // 32 KB
    float* A_lds = smem;                 // [KC][128] transposed, col-swizzled
    float* B_lds = smem + KC * 128;      // [KC][UT]  quad-swizzled

    const int tid = threadIdx.x;
    const int tx  = tid & 15;            // unit group
    const int ty  = tid >> 4;            // token group (0..15)
    const int bid = blockIdx.x;

    const bool is_att = bid < ATT_BLOCKS;
    const int  lb     = is_att ? bid : bid - ATT_BLOCKS;
    const int  tile   = is_att ? (lb >> 2) : (lb >> 1);   // consecutive bids share A tile
    const int  pass   = is_att ? (lb & 3)  : (lb & 1);
    const int  slot   = is_att ? pass : 4 + pass;
    const int  tokb   = tile * TT;
    const int  u0     = pass * UT;
    const int  wstride = is_att ? NA : NI;

    const float* Aptr = is_att ? keys : values;
    const float* Wptr = (is_att ? W1a : W1i) + u0;
    const float* b1p  = (is_att ? b1a : b1i) + u0;
    const float* w2p  = (is_att ? W2a : W2i) + u0;

    float acc[8][8];
#pragma unroll
    for (int t = 0; t < 8; ++t)
#pragma unroll
        for (int u = 0; u < 8; ++u) acc[t][u] = 0.f;

    // A staging map: at = token 0..31 (+32p), aq = f4 index within 32-h row.
    const int at = tid >> 3;
    const int aq = tid & 7;
    const float* a_base = Aptr + (size_t)(tokb + at) * H + aq * 4;
    // col_phys = at ^ ((aq&3)<<3)  (XOR — bijective within each 32-col group;
    // the p*32 term only touches bits >=5 so it adds cleanly on top)
    float* aw = A_lds + (aq * 4) * 128 + (at ^ ((aq & 3) << 3));

    // B staging map: row rb (+8p), quad q = tid&31 -> swizzled position.
    const int bqi = tid & 31;
    const int rb  = tid >> 5;
    const float* b_base = Wptr + (size_t)rb * wstride + bqi * 4;
    float* bw = B_lds + rb * UT + ((bqi ^ (bqi >> 3)) << 2);
    // B read offsets (constant per thread): quads 2tx, 2tx+1 swizzled
    const int q1 = 2 * tx, q2 = 2 * tx + 1;
    const int boff1 = ((q1 ^ (q1 >> 3)) << 2);
    const int boff2 = ((q2 ^ (q2 >> 3)) << 2);

    for (int h0 = 0; h0 < H; h0 += KC) {
        // issue global loads early (reg dest); overlap the barrier wait
        float4 aR[4], bR[4];
#pragma unroll
        for (int p = 0; p < 4; ++p)
            aR[p] = *(const float4*)(a_base + h0 + (size_t)p * 32 * H);
#pragma unroll
        for (int p = 0; p < 4; ++p)
            bR[p] = *(const float4*)(b_base + (size_t)(h0 + p * 8) * wstride);

        __syncthreads();                 // previous chunk fully consumed
#pragma unroll
        for (int p = 0; p < 4; ++p) {
            aw[0 * 128 + p * 32] = aR[p].x;
            aw[1 * 128 + p * 32] = aR[p].y;
            aw[2 * 128 + p * 32] = aR[p].z;
            aw[3 * 128 + p * 32] = aR[p].w;
        }
#pragma unroll
        for (int p = 0; p < 4; ++p)
            *(float4*)&bw[p * 8 * UT] = bR[p];
        __syncthreads();

#pragma unroll 8
        for (int h = 0; h < KC; ++h) {
            const int tys = ((ty ^ ((h >> 2) & 3)) << 3);   // compile-time per unrolled h
            float a[8], b[8];
            *(float4*)&a[0] = *(const float4*)&A_lds[h * 128 + tys];
            *(float4*)&a[4] = *(const float4*)&A_lds[h * 128 + tys + 4];
            *(float4*)&b[0] = *(const float4*)&B_lds[h * UT + boff1];
            *(float4*)&b[4] = *(const float4*)&B_lds[h * UT + boff2];
#pragma unroll
            for (int t = 0; t < 8; ++t)
#pragma unroll
                for (int u = 0; u < 8; ++u)
                    acc[t][u] = fmaf(a[t], b[u], acc[t][u]);
        }
    }

    // ---- epilogue: relu + second-layer slice -> per-token partial ----
    float b1v[8], w2v[8];
    *(float4*)&b1v[0] = *(const float4*)(b1p + tx * 8);
    *(float4*)&b1v[4] = *(const float4*)(b1p + tx * 8 + 4);
    *(float4*)&w2v[0] = *(const float4*)(w2p + tx * 8);
    *(float4*)&w2v[4] = *(const float4*)(w2p + tx * 8 + 4);

    __syncthreads();                     // done with staging LDS
    float* red = smem;                   // [TT][17] padded
#pragma unroll
    for (int t = 0; t < 8; ++t) {
        float s = 0.f;
#pragma unroll
        for (int u = 0; u < 8; ++u)
            s += fmaxf(acc[t][u] + b1v[u], 0.f) * w2v[u];
        red[(ty * 8 + t) * 17 + tx] = s;
    }
    __syncthreads();
    if (tid < TT) {
        float s = 0.f;
        for (int x = 0; x < 16; ++x) s += red[tid * 17 + x];   // fixed order
        part[(size_t)slot * NTOK + tokb + tid] = s;
    }
}

// ---------------------------------------------------------------------------
// block-wide sum (256 threads), result broadcast to all threads
// ---------------------------------------------------------------------------
__device__ __forceinline__ int block_sum(int val, int* red, int tid)
{
#pragma unroll
    for (int off = 32; off > 0; off >>= 1) val += __shfl_down(val, off);
    if ((tid & 63) == 0) red[tid >> 6] = val;
    __syncthreads();
    const int total = red[0] + red[1] + red[2] + red[3];
    __syncthreads();
    return total;
}

// ---------------------------------------------------------------------------
// Kernel 2: combine partials into scores (fixed order) + per-row exact
// top-KSEL via 4-pass byte-radix select with parallel scans -> float mask.
// ---------------------------------------------------------------------------
__global__ __launch_bounds__(256) void select_kernel(
    const float* __restrict__ part, const float* __restrict__ b2a,
    const float* __restrict__ b2i, float* __restrict__ mask)
{
    __shared__ unsigned int ks[MIDN];
    __shared__ int hist[256];
    __shared__ int red[4];
    __shared__ int scan_s[256];
    __shared__ unsigned int sh_pref;
    __shared__ int sh_r;

    const int tid = threadIdx.x;
    const int row = blockIdx.x;
    const float ba  = b2a[0];
    const float bi2 = b2i[0];

    for (int i = tid; i < MIDN; i += 256) {
        const int tok = row * SEQ + SINKN + i;
        float sa = ((part[tok] + part[NTOK + tok]) + part[2 * NTOK + tok]) + part[3 * NTOK + tok];
        float si = part[4 * NTOK + tok] + part[5 * NTOK + tok];
        const float att = 1.f / (1.f + expf(-(sa + ba)));
        const float s = 0.6f * att + 0.4f * (si + bi2);
        unsigned int u = __float_as_uint(s);
        u = (u & 0x80000000u) ? ~u : (u | 0x80000000u);   // order-preserving map
        ks[i] = u;
    }
    if (tid == 0) { sh_pref = 0u; sh_r = KSEL; }
    __syncthreads();

    // byte-radix: after 4 passes sh_pref == KSEL-th largest key value
    for (int b = 3; b >= 0; --b) {
        hist[tid] = 0;
        __syncthreads();
        const unsigned int hi_mask = (b == 3) ? 0u : (0xFFFFFFFFu << ((b + 1) * 8));
        const unsigned int pref = sh_pref;
        for (int i = tid; i < MIDN; i += 256) {
            const unsigned int u = ks[i];
            if ((u & hi_mask) == pref)
                atomicAdd(&hist[(u >> (b * 8)) & 255], 1);
        }
        __syncthreads();

        // inclusive suffix-sum of hist (Hillis-Steele, 8 rounds)
        scan_s[tid] = hist[tid];
        __syncthreads();
#pragma unroll
        for (int off = 1; off < 256; off <<= 1) {
            const int add = (tid + off < 256) ? scan_s[tid + off] : 0;
            __syncthreads();
            scan_s[tid] += add;
            __syncthreads();
        }
        const int r    = sh_r;
        const int sfx  = scan_s[tid];
        const int sfx1 = (tid < 255) ? scan_s[tid + 1] : 0;
        if (sfx >= r && sfx1 < r) {      // unique winner
            sh_r = r - sfx1;
            sh_pref = pref | ((unsigned int)tid << (b * 8));
        }
        __syncthreads();
    }
    const unsigned int v = sh_pref;

    const int st = tid * CHK;
    const int en = (st + CHK < MIDN) ? (st + CHK) : MIDN;

    int cgt = 0, ceq = 0;
    for (int k = st; k < en; ++k) { cgt += (ks[k] > v) ? 1 : 0; ceq += (ks[k] == v) ? 1 : 0; }
    const int total_gt = block_sum(cgt, red, tid);
    const int need = KSEL - total_gt;    // #ties to keep (>=1 by construction)

    // exclusive prefix-sum of tie counts (parallel)
    scan_s[tid] = ceq;
    __syncthreads();
#pragma unroll
    for (int off = 1; off < 256; off <<= 1) {
        const int add = (tid >= off) ? scan_s[tid - off] : 0;
        __syncthreads();
        scan_s[tid] += add;
        __syncthreads();
    }
    int r = scan_s[tid] - ceq;           // exclusive prefix

    float* mr = mask + row * SEQ;
    for (int k = st; k < en; ++k) {
        const unsigned int u = ks[k];
        bool keep = false;
        if (u > v) keep = true;
        else if (u == v) { keep = (r < need); ++r; }
        mr[SINKN + k] = keep ? 1.f : 0.f;
    }
    for (int s = tid; s < SEQ; s += 256) {
        if (s < SINKN || s >= SEQ - RECENTN) mr[s] = 1.f;
    }
}

// ---------------------------------------------------------------------------
// Kernel 3: out = concat(keys*mask, values*mask), float4 grid-stride.
// ---------------------------------------------------------------------------
__global__ __launch_bounds__(256) void apply_kernel(
    const float* __restrict__ keys, const float* __restrict__ values,
    const float* __restrict__ mask, float* __restrict__ out)
{
    const int QT = NTOK * H / 4;          // 4194304 float4 per tensor
    const int stride = gridDim.x * 256;
    for (int i4 = blockIdx.x * 256 + threadIdx.x; i4 < 2 * QT; i4 += stride) {
        const bool isv = (i4 >= QT);
        const int  j4  = isv ? (i4 - QT) : i4;
        const float m  = mask[j4 >> 8];   // 256 float4 per token row
        const float4* src = isv ? (const float4*)values : (const float4*)keys;
        const float4 x = src[j4];
        float4 y; y.x = x.x * m; y.y = x.y * m; y.z = x.z * m; y.w = x.w * m;
        ((float4*)out)[i4] = y;
    }
}

extern "C" void kernel_launch(void* const* d_in, const int* in_sizes, int n_in,
                              void* d_out, int out_size, void* d_ws, size_t ws_size,
                              hipStream_t stream)
{
    const float* keys   = (const float*)d_in[0];
    const float* values = (const float*)d_in[1];
    const float* W1a = (const float*)d_in[2];
    const float* b1a = (const float*)d_in[3];
    const float* W2a = (const float*)d_in[4];
    const float* b2a = (const float*)d_in[5];
    const float* W1i = (const float*)d_in[6];
    const float* b1i = (const float*)d_in[7];
    const float* W2i = (const float*)d_in[8];
    const float* b2i = (const float*)d_in[9];

    float* part = (float*)d_ws;            // 6*NTOK floats (att 0-3, imp 4-5)
    float* mask = part + 6 * NTOK;         // NTOK floats

    score_gemm_kernel<<<ATT_BLOCKS + IMP_BLOCKS, 256, 0, stream>>>(
        keys, values, W1a, b1a, W2a, W1i, b1i, W2i, part);
    select_kernel<<<BATCH, 256, 0, stream>>>(part, b2a, b2i, mask);
    apply_kernel<<<8192, 256, 0, stream>>>(keys, values, mask, (float*)d_out);
}

// Round 6
// 542.483 us; speedup vs baseline: 1.0480x; 1.0480x over previous
//
#include <hip/hip_runtime.h>
#include <math.h>

#define H      1024
#define NA     512
#define NI     256
#define SEQ    4096
#define BATCH  4
#define NTOK   (BATCH*SEQ)      // 16384
#define SINKN  4
#define RECENTN 19
#define MIDN   (SEQ - SINKN - RECENTN)   // 4073
#define KSEL   2025
#define CHK    16

#define TT   128                // tokens per tile
#define UT   128                // units per tile
#define KC   32                 // k-chunk staged in LDS
#define NCH  (H/KC)             // 32 chunks
#define ATT_BLOCKS ((NTOK/TT) * (NA/UT))   // 512
#define IMP_BLOCKS ((NTOK/TT) * (NI/UT))   // 256

// async global->LDS, 16B per lane, dest = uniform base + lane*16
__device__ __forceinline__ void dma16(const float* g, float* l)
{
    __builtin_amdgcn_global_load_lds(
        (const __attribute__((address_space(1))) void*)g,
        (__attribute__((address_space(3))) void*)l, 16, 0, 0);
}

// ---------------------------------------------------------------------------
// Kernel 1 (v6, resubmitted unchanged after infra failure): 128x128 tile GEMM,
// 8x8 per-thread, conflict-free LDS.
// Diagnosis from v5 counters: LDS-pipe-bound (590K read-cyc/CU) + 28M conflict
// cycles (B-reads: 16 addrs over 8 bank-groups) + 195MB scratch (float4
// ARRAYS aR[]/bR[] not promoted to regs).
// v6:
//  - lane remap: token-octet = lane>>3 (+8*(w&1)), unit-octet = lane&7
//    (+8*(w>>1)) -> A and B reads are both 8-address b128 patterns.
//  - Gray quad-swizzle: logical quad q stored at phys quad gray(q)=q^(q>>1)
//    (A additionally XORed by rho=h>>2 per row). gray(2k) and gray(2k+1) are
//    bijective mod 8 -> all 4 b128 reads/h hit 8 distinct bank-groups: ZERO
//    conflicts. A-writes land 2-way (free).
//  - B staged by global_load_lds DMA: linear LDS dest, per-lane global source
//    pre-swizzled by gray^-1 (prefix-XOR) -> read addressing = gray(u), no
//    staging VGPRs, no ds_write for B. B double-buffered (LDS 48KB).
//  - A prefetch in 4 NAMED float4 scalars (arrays spilled to scratch in v3-v5).
//  - pipeline: [bar1: drain old loads] A-writes [bar2: nothing in flight]
//    issue next A-loads + B-DMA, then compute -> barriers drain cheap.
// Per-thread (token,unit) sets and all summation orders identical to v5 ->
// scores bit-identical -> mask identical.
// ---------------------------------------------------------------------------
__global__ __launch_bounds__(256, 2) void score_gemm_kernel(
    const float* __restrict__ keys, const float* __restrict__ values,
    const float* __restrict__ W1a, const float* __restrict__ b1a,
    const float* __restrict__ W2a,
    const float* __restrict__ W1i, const float* __restrict__ b1i,
    const float* __restrict__ W2i,
    float* __restrict__ part)
{
    __shared__ __align__(16) float smem[KC * 128 + 2 * KC * 128];   // 48 KB
    float* A_lds = smem;                 // [KC][128] transposed, gray-swizzled
    float* Bbuf  = smem + KC * 128;      // 2 x [KC][128], linear (DMA), gray-sourced

    const int tid = threadIdx.x;
    const int lw  = tid & 63;            // lane in wave
    const int w   = tid >> 6;            // wave 0..3
    const int bid = blockIdx.x;

    const bool is_att = bid < ATT_BLOCKS;
    const int  lb     = is_att ? bid : bid - ATT_BLOCKS;
    const int  tile   = is_att ? (lb >> 2) : (lb >> 1);
    const int  pass   = is_att ? (lb & 3)  : (lb & 1);
    const int  slot   = is_att ? pass : 4 + pass;
    const int  tokb   = tile * TT;
    const int  u0     = pass * UT;
    const int  wstride = is_att ? NA : NI;

    const float* Aptr = is_att ? keys : values;
    const float* Wptr = (is_att ? W1a : W1i) + u0;
    const float* b1p  = (is_att ? b1a : b1i) + u0;
    const float* w2p  = (is_att ? W2a : W2i) + u0;

    // 8x8 octet split: this thread owns tokens 8*T8..+7, units 8*U8..+7
    const int T8 = (lw >> 3) | ((w & 1) << 3);   // 0..15
    const int U8 = (lw & 7)  | ((w >> 1) << 3);  // 0..15

    // fragment read offsets (gray of the two quads per side)
    const int qA1 = 2 * T8,      qA2 = 2 * T8 + 1;
    const int gA1 = qA1 ^ (qA1 >> 1);
    const int gA2 = qA2 ^ (qA2 >> 1);
    const int qB1 = 2 * U8,      qB2 = 2 * U8 + 1;
    const int gB1 = (qB1 ^ (qB1 >> 1)) << 2;     // float offset in row
    const int gB2 = (qB2 ^ (qB2 >> 1)) << 2;

    // A staging: thread loads tokens {at, at+32, at+64, at+96}, h-quad aq
    const int at = tid >> 3;             // 0..31
    const int aq = tid & 7;              // h-quad within chunk; rho(h)=h>>2
    const float* a_base = Aptr + (size_t)(tokb + at) * H + aq * 4;
    const int awb = (aq * 4) * 128 + (at & 3);
    const int at4 = at >> 2;
    const int q50 = at4,      q51 = at4 + 8, q52 = at4 + 16, q53 = at4 + 24;
    const int of0 = (((q50 ^ (q50 >> 1)) ^ aq) << 2);
    const int of1 = (((q51 ^ (q51 >> 1)) ^ aq) << 2);
    const int of2 = (((q52 ^ (q52 >> 1)) ^ aq) << 2);
    const int of3 = (((q53 ^ (q53 >> 1)) ^ aq) << 2);

    // B DMA: lane lw writes LDS bytes [base+16*lw) = row (lw>>5), slot (lw&31).
    // slot s must hold W quad pi(s) = gray^-1(s) (prefix-XOR).
    const int sl   = lw & 31;
    const int pisl = sl ^ (sl >> 1) ^ (sl >> 2) ^ (sl >> 3) ^ (sl >> 4);
    const float* bg = Wptr + (size_t)(lw >> 5) * wstride + pisl * 4;
    const int wrow = 8 * w;              // this wave's B row base within chunk

    float acc[8][8];
#pragma unroll
    for (int t = 0; t < 8; ++t)
#pragma unroll
        for (int u = 0; u < 8; ++u) acc[t][u] = 0.f;

    // ---- prologue: chunk 0 in flight ----
    float4 aR0 = *(const float4*)(a_base);
    float4 aR1 = *(const float4*)(a_base + (size_t)32 * H);
    float4 aR2 = *(const float4*)(a_base + (size_t)64 * H);
    float4 aR3 = *(const float4*)(a_base + (size_t)96 * H);
    dma16(bg + (size_t)(wrow + 0) * wstride, Bbuf + (wrow + 0) * 128);
    dma16(bg + (size_t)(wrow + 2) * wstride, Bbuf + (wrow + 2) * 128);
    dma16(bg + (size_t)(wrow + 4) * wstride, Bbuf + (wrow + 4) * 128);
    dma16(bg + (size_t)(wrow + 6) * wstride, Bbuf + (wrow + 6) * 128);

    for (int i = 0; i < NCH; ++i) {
        float* Bcur = Bbuf + (i & 1) * (KC * 128);
        float* Bnxt = Bbuf + ((i + 1) & 1) * (KC * 128);

        __syncthreads();     // drains loads issued a full compute-phase ago
        A_lds[awb + 0 * 128 + of0] = aR0.x;
        A_lds[awb + 1 * 128 + of0] = aR0.y;
        A_lds[awb + 2 * 128 + of0] = aR0.z;
        A_lds[awb + 3 * 128 + of0] = aR0.w;
        A_lds[awb + 0 * 128 + of1] = aR1.x;
        A_lds[awb + 1 * 128 + of1] = aR1.y;
        A_lds[awb + 2 * 128 + of1] = aR1.z;
        A_lds[awb + 3 * 128 + of1] = aR1.w;
        A_lds[awb + 0 * 128 + of2] = aR2.x;
        A_lds[awb + 1 * 128 + of2] = aR2.y;
        A_lds[awb + 2 * 128 + of2] = aR2.z;
        A_lds[awb + 3 * 128 + of2] = aR2.w;
        A_lds[awb + 0 * 128 + of3] = aR3.x;
        A_lds[awb + 1 * 128 + of3] = aR3.y;
        A_lds[awb + 2 * 128 + of3] = aR3.z;
        A_lds[awb + 3 * 128 + of3] = aR3.w;
        __syncthreads();     // nothing in vmem flight -> cheap drain

        if (i + 1 < NCH) {   // issue next chunk; lands by next top-barrier
            const int hn = (i + 1) * KC;
            aR0 = *(const float4*)(a_base + hn);
            aR1 = *(const float4*)(a_base + hn + (size_t)32 * H);
            aR2 = *(const float4*)(a_base + hn + (size_t)64 * H);
            aR3 = *(const float4*)(a_base + hn + (size_t)96 * H);
            const float* bgn = bg + (size_t)hn * wstride;
            dma16(bgn + (size_t)(wrow + 0) * wstride, Bnxt + (wrow + 0) * 128);
            dma16(bgn + (size_t)(wrow + 2) * wstride, Bnxt + (wrow + 2) * 128);
            dma16(bgn + (size_t)(wrow + 4) * wstride, Bnxt + (wrow + 4) * 128);
            dma16(bgn + (size_t)(wrow + 6) * wstride, Bnxt + (wrow + 6) * 128);
        }

#pragma unroll 8
        for (int h = 0; h < KC; ++h) {
            const int rho = h >> 2;
            float a[8], b[8];
            *(float4*)&a[0] = *(const float4*)&A_lds[h * 128 + ((gA1 ^ rho) << 2)];
            *(float4*)&a[4] = *(const float4*)&A_lds[h * 128 + ((gA2 ^ rho) << 2)];
            *(float4*)&b[0] = *(const float4*)&Bcur[h * 128 + gB1];
            *(float4*)&b[4] = *(const float4*)&Bcur[h * 128 + gB2];
#pragma unroll
            for (int t = 0; t < 8; ++t)
#pragma unroll
                for (int u = 0; u < 8; ++u)
                    acc[t][u] = fmaf(a[t], b[u], acc[t][u]);
        }
    }

    // ---- epilogue: relu + second-layer slice -> per-token partial ----
    float b1v[8], w2v[8];
    *(float4*)&b1v[0] = *(const float4*)(b1p + U8 * 8);
    *(float4*)&b1v[4] = *(const float4*)(b1p + U8 * 8 + 4);
    *(float4*)&w2v[0] = *(const float4*)(w2p + U8 * 8);
    *(float4*)&w2v[4] = *(const float4*)(w2p + U8 * 8 + 4);

    __syncthreads();                     // done with staging LDS
    float* red = smem;                   // [TT][17] padded
#pragma unroll
    for (int t = 0; t < 8; ++t) {
        float s = 0.f;
#pragma unroll
        for (int u = 0; u < 8; ++u)
            s += fmaxf(acc[t][u] + b1v[u], 0.f) * w2v[u];
        red[(T8 * 8 + t) * 17 + U8] = s;
    }
    __syncthreads();
    if (tid < TT) {
        float s = 0.f;
        for (int x = 0; x < 16; ++x) s += red[tid * 17 + x];   // fixed order
        part[(size_t)slot * NTOK + tokb + tid] = s;
    }
}

// ---------------------------------------------------------------------------
// block-wide sum (256 threads), result broadcast to all threads
// ---------------------------------------------------------------------------
__device__ __forceinline__ int block_sum(int val, int* red, int tid)
{
#pragma unroll
    for (int off = 32; off > 0; off >>= 1) val += __shfl_down(val, off);
    if ((tid & 63) == 0) red[tid >> 6] = val;
    __syncthreads();
    const int total = red[0] + red[1] + red[2] + red[3];
    __syncthreads();
    return total;
}

// ---------------------------------------------------------------------------
// Kernel 2: combine partials into scores (fixed order) + per-row exact
// top-KSEL via 4-pass byte-radix select with parallel scans -> float mask.
// ---------------------------------------------------------------------------
__global__ __launch_bounds__(256) void select_kernel(
    const float* __restrict__ part, const float* __restrict__ b2a,
    const float* __restrict__ b2i, float* __restrict__ mask)
{
    __shared__ unsigned int ks[MIDN];
    __shared__ int hist[256];
    __shared__ int red[4];
    __shared__ int scan_s[256];
    __shared__ unsigned int sh_pref;
    __shared__ int sh_r;

    const int tid = threadIdx.x;
    const int row = blockIdx.x;
    const float ba  = b2a[0];
    const float bi2 = b2i[0];

    for (int i = tid; i < MIDN; i += 256) {
        const int tok = row * SEQ + SINKN + i;
        float sa = ((part[tok] + part[NTOK + tok]) + part[2 * NTOK + tok]) + part[3 * NTOK + tok];
        float si = part[4 * NTOK + tok] + part[5 * NTOK + tok];
        const float att = 1.f / (1.f + expf(-(sa + ba)));
        const float s = 0.6f * att + 0.4f * (si + bi2);
        unsigned int u = __float_as_uint(s);
        u = (u & 0x80000000u) ? ~u : (u | 0x80000000u);   // order-preserving map
        ks[i] = u;
    }
    if (tid == 0) { sh_pref = 0u; sh_r = KSEL; }
    __syncthreads();

    // byte-radix: after 4 passes sh_pref == KSEL-th largest key value
    for (int b = 3; b >= 0; --b) {
        hist[tid] = 0;
        __syncthreads();
        const unsigned int hi_mask = (b == 3) ? 0u : (0xFFFFFFFFu << ((b + 1) * 8));
        const unsigned int pref = sh_pref;
        for (int i = tid; i < MIDN; i += 256) {
            const unsigned int u = ks[i];
            if ((u & hi_mask) == pref)
                atomicAdd(&hist[(u >> (b * 8)) & 255], 1);
        }
        __syncthreads();

        // inclusive suffix-sum of hist (Hillis-Steele, 8 rounds)
        scan_s[tid] = hist[tid];
        __syncthreads();
#pragma unroll
        for (int off = 1; off < 256; off <<= 1) {
            const int add = (tid + off < 256) ? scan_s[tid + off] : 0;
            __syncthreads();
            scan_s[tid] += add;
            __syncthreads();
        }
        const int r    = sh_r;
        const int sfx  = scan_s[tid];
        const int sfx1 = (tid < 255) ? scan_s[tid + 1] : 0;
        if (sfx >= r && sfx1 < r) {      // unique winner
            sh_r = r - sfx1;
            sh_pref = pref | ((unsigned int)tid << (b * 8));
        }
        __syncthreads();
    }
    const unsigned int v = sh_pref;

    const int st = tid * CHK;
    const int en = (st + CHK < MIDN) ? (st + CHK) : MIDN;

    int cgt = 0, ceq = 0;
    for (int k = st; k < en; ++k) { cgt += (ks[k] > v) ? 1 : 0; ceq += (ks[k] == v) ? 1 : 0; }
    const int total_gt = block_sum(cgt, red, tid);
    const int need = KSEL - total_gt;    // #ties to keep (>=1 by construction)

    // exclusive prefix-sum of tie counts (parallel)
    scan_s[tid] = ceq;
    __syncthreads();
#pragma unroll
    for (int off = 1; off < 256; off <<= 1) {
        const int add = (tid >= off) ? scan_s[tid - off] : 0;
        __syncthreads();
        scan_s[tid] += add;
        __syncthreads();
    }
    int r = scan_s[tid] - ceq;           // exclusive prefix

    float* mr = mask + row * SEQ;
    for (int k = st; k < en; ++k) {
        const unsigned int u = ks[k];
        bool keep = false;
        if (u > v) keep = true;
        else if (u == v) { keep = (r < need); ++r; }
        mr[SINKN + k] = keep ? 1.f : 0.f;
    }
    for (int s = tid; s < SEQ; s += 256) {
        if (s < SINKN || s >= SEQ - RECENTN) mr[s] = 1.f;
    }
}

// ---------------------------------------------------------------------------
// Kernel 3: out = concat(keys*mask, values*mask), float4 grid-stride.
// ---------------------------------------------------------------------------
__global__ __launch_bounds__(256) void apply_kernel(
    const float* __restrict__ keys, const float* __restrict__ values,
    const float* __restrict__ mask, float* __restrict__ out)
{
    const int QT = NTOK * H / 4;          // 4194304 float4 per tensor
    const int stride = gridDim.x * 256;
    for (int i4 = blockIdx.x * 256 + threadIdx.x; i4 < 2 * QT; i4 += stride) {
        const bool isv = (i4 >= QT);
        const int  j4  = isv ? (i4 - QT) : i4;
        const float m  = mask[j4 >> 8];   // 256 float4 per token row
        const float4* src = isv ? (const float4*)values : (const float4*)keys;
        const float4 x = src[j4];
        float4 y; y.x = x.x * m; y.y = x.y * m; y.z = x.z * m; y.w = x.w * m;
        ((float4*)out)[i4] = y;
    }
}

extern "C" void kernel_launch(void* const* d_in, const int* in_sizes, int n_in,
                              void* d_out, int out_size, void* d_ws, size_t ws_size,
                              hipStream_t stream)
{
    const float* keys   = (const float*)d_in[0];
    const float* values = (const float*)d_in[1];
    const float* W1a = (const float*)d_in[2];
    const float* b1a = (const float*)d_in[3];
    const float* W2a = (const float*)d_in[4];
    const float* b2a = (const float*)d_in[5];
    const float* W1i = (const float*)d_in[6];
    const float* b1i = (const float*)d_in[7];
    const float* W2i = (const float*)d_in[8];
    const float* b2i = (const float*)d_in[9];

    float* part = (float*)d_ws;            // 6*NTOK floats (att 0-3, imp 4-5)
    float* mask = part + 6 * NTOK;         // NTOK floats

    score_gemm_kernel<<<ATT_BLOCKS + IMP_BLOCKS, 256, 0, stream>>>(
        keys, values, W1a, b1a, W2a, W1i, b1i, W2i, part);
    select_kernel<<<BATCH, 256, 0, stream>>>(part, b2a, b2i, mask);
    apply_kernel<<<8192, 256, 0, stream>>>(keys, values, mask, (float*)d_out);
}